// Round 4
// baseline (73.342 us; speedup 1.0000x reference)
//
#include <hip/hip_runtime.h>

#define N_ROWS 128
#define IN_DIM 1024
#define OUT_DIM 1024

// out[n,o] = max_k(w[o,k] + x[n,k]) + bias[o]   (tropical matmul)
//
// Bottleneck analysis (R3): LDS instruction throughput. ds_read_b128 count =
// triples/64/No. R3 had No=1 -> 524k instrs -> 10.2 us on the LDS pipe.
// This version: No=4 o-columns per lane per x-read -> 131k -> 2.56 us,
// balancing the 2.56 us VALU floor.
//
// Lane: g = lane&15 (k-phase), og = lane>>4 (o offset 0..3).
// Lane handles o = ob + c*4 + og for c=0..3; per k-step t reads
// xs[j*256 + t*16 + g] once and does 4 o x 6 VALU with register-held w.
// w loads: per (c,t) lanes g=0..15 read 256 B contiguous of row o_c
// (coalesced, 4 rows/instr), double-buffered across t.
// Block: 128 threads = 2 waves (o-span 32), x tile 8n x 4KB = 32 KB LDS.
// Grid: 16 bn x 32 bo = 512 blocks (bo minor) -> 2 blocks/CU; XCD =
// blockIdx%8 = bo%8 so all 16 bn-blocks sharing a w column-band land on one
// XCD (512 KB w per XCD L2).
// Epilogue: butterfly max over g (xor 1,2,4,8), g==0 lanes (og 0..3) store.

__global__ __launch_bounds__(128, 1)
void tropical_linear_kernel(const float* __restrict__ x,
                            const float* __restrict__ w,
                            const float* __restrict__ bias,
                            float* __restrict__ out) {
    __shared__ float4 xs[8 * 256];   // 32 KB

    const int tid  = threadIdx.x;
    const int wid  = tid >> 6;       // wave 0..1
    const int lane = tid & 63;
    const int g    = lane & 15;      // k phase 0..15
    const int og   = lane >> 4;      // o offset 0..3

    const int bn = blockIdx.x >> 5;  // 16 n-blocks
    const int bo = blockIdx.x & 31;  // 32 o-blocks (minor -> XCD locality)
    const int n0 = bn * 8;
    const int ob = bo * 32 + wid * 16;

    const float4* __restrict__ x4 = (const float4*)x;

    // ---- stage x tile: 2048 float4, 16 per thread, coalesced ----
#pragma unroll
    for (int i = 0; i < 16; ++i) {
        const int idx = tid + i * 128;
        const int r = idx >> 8, c = idx & 255;
        xs[idx] = x4[(size_t)(n0 + r) * 256 + c];
    }
    __syncthreads();

    float acc[4][8];
#pragma unroll
    for (int c = 0; c < 4; ++c)
#pragma unroll
        for (int j = 0; j < 8; ++j) acc[c][j] = -3.4e38f;

    const float4* __restrict__ wr[4];
#pragma unroll
    for (int c = 0; c < 4; ++c)
        wr[c] = (const float4*)(w + (size_t)(ob + c * 4 + og) * IN_DIM);

    // ---- K loop: 16 steps of 64 k (16 g-lanes x float4), w double-buffered
    float4 wcur[4], wnxt[4];
#pragma unroll
    for (int c = 0; c < 4; ++c) wcur[c] = wr[c][g];

#pragma unroll 2
    for (int t = 0; t < 16; ++t) {
        if (t < 15) {
#pragma unroll
            for (int c = 0; c < 4; ++c) wnxt[c] = wr[c][(t + 1) * 16 + g];
        }
        const int kq = t * 16 + g;
#pragma unroll
        for (int j = 0; j < 8; ++j) {
            const float4 xv = xs[j * 256 + kq];
#pragma unroll
            for (int c = 0; c < 4; ++c) {
                const float s0 = wcur[c].x + xv.x;
                const float s1 = wcur[c].y + xv.y;
                const float s2 = wcur[c].z + xv.z;
                const float s3 = wcur[c].w + xv.w;
                const float m = fmaxf(fmaxf(s0, s1), s2);   // v_max3
                acc[c][j] = fmaxf(fmaxf(m, s3), acc[c][j]); // v_max3
            }
        }
#pragma unroll
        for (int c = 0; c < 4; ++c) wcur[c] = wnxt[c];
    }

    // ---- reduce across the 16 k-phases (lane bits 0..3) ----
#pragma unroll
    for (int c = 0; c < 4; ++c)
#pragma unroll
        for (int j = 0; j < 8; ++j) {
            float v = acc[c][j];
            v = fmaxf(v, __shfl_xor(v, 1, 64));
            v = fmaxf(v, __shfl_xor(v, 2, 64));
            v = fmaxf(v, __shfl_xor(v, 4, 64));
            v = fmaxf(v, __shfl_xor(v, 8, 64));
            acc[c][j] = v;
        }

    if (g == 0) {
#pragma unroll
        for (int c = 0; c < 4; ++c) {
            const int o = ob + c * 4 + og;
            const float b = bias[o];
#pragma unroll
            for (int j = 0; j < 8; ++j) {
                out[(size_t)(n0 + j) * OUT_DIM + o] = acc[c][j] + b;
            }
        }
    }
}

extern "C" void kernel_launch(void* const* d_in, const int* in_sizes, int n_in,
                              void* d_out, int out_size, void* d_ws, size_t ws_size,
                              hipStream_t stream) {
    const float* x    = (const float*)d_in[0];   // [128,1024]
    const float* w    = (const float*)d_in[1];   // [1024,1024]
    const float* bias = (const float*)d_in[2];   // [1024]
    float* out = (float*)d_out;                  // [128,1024]

    dim3 grid(512);
    dim3 block(128);
    hipLaunchKernelGGL(tropical_linear_kernel, grid, block, 0, stream, x, w, bias, out);
}

// Round 5
// 69.271 us; speedup vs baseline: 1.0588x; 1.0588x over previous
//
#include <hip/hip_runtime.h>

#define N_ROWS 128
#define IN_DIM 1024
#define OUT_DIM 1024

// out[n,o] = max_k(w[o,k] + x[n,k]) + bias[o]   (tropical matmul)
//
// Pipe model per CU (256 CUs): VALU 3.15M instr -> 2.56 us/SIMD;
// ds_read_b128 = 524k/No -> No=4 gives 131k -> 2.56 us; w L2 traffic =
// (128/j_tile)*4MB -> j_tile=8 gives 64 MB -> ~1.9 us. Need >=4 waves/SIMD
// to hide LDS (~120cyc) + global (~300cyc) latency (R4 lesson).
//
// Block: 256 thr = 4 waves, ALL covering the same 8n x 16o tile; waves
// split K into quarters (256 k each) -> 1024 blocks x 4 waves = 4096 waves
// = 16 waves/CU = 4/SIMD, with zero extra w traffic (disjoint k-slices).
// Lane: g = lane&15 (k-phase within quarter), og = lane>>4 (o low bits).
// Lane accumulates acc[c][j] for o = ob + c*4 + og (c=0..3), j=0..7 n-rows.
// Per t-step: 1 ds_read_b128 per j feeds 4 o's (24 VALU); w float4 x4
// double-buffered from global (coalesced: g-lanes = 256 B contiguous/row).
// Epilogue: butterfly max over g (xor 1,2,4,8) then cross-wave max via LDS
// (exact: max is associative), bias add, coalesced store.
// Grid: bn*64+bo (bo minor) -> same-bo blocks share an XCD (512 KB w/XCD L2).

__global__ __launch_bounds__(256, 4)
void tropical_linear_kernel(const float* __restrict__ x,
                            const float* __restrict__ w,
                            const float* __restrict__ bias,
                            float* __restrict__ out) {
    __shared__ float4 xs[8 * 256];          // 32 KB x-tile (8 rows, full K)
    __shared__ float red[4 * 4 * 4 * 8];    // [wid][og][c][j] = 2 KB

    const int tid  = threadIdx.x;
    const int wid  = tid >> 6;       // wave 0..3 = k-quarter
    const int lane = tid & 63;
    const int g    = lane & 15;      // k phase 0..15
    const int og   = lane >> 4;      // o offset 0..3

    const int bn = blockIdx.x >> 6;  // 16 n-blocks
    const int bo = blockIdx.x & 63;  // 64 o-blocks (minor -> XCD locality)
    const int n0 = bn * 8;
    const int ob = bo * 16;

    const float4* __restrict__ x4 = (const float4*)x;

    // ---- stage x tile: 2048 float4, 8 per thread, coalesced ----
#pragma unroll
    for (int i = 0; i < 8; ++i) {
        const int idx = tid + i * 256;
        const int r = idx >> 8, c = idx & 255;
        xs[idx] = x4[(size_t)(n0 + r) * 256 + c];
    }
    __syncthreads();

    float acc[4][8];
#pragma unroll
    for (int c = 0; c < 4; ++c)
#pragma unroll
        for (int j = 0; j < 8; ++j) acc[c][j] = -3.4e38f;

    const int kq0 = wid * 64;        // this wave's k-quarter (float4 units)
    const float4* __restrict__ wr[4];
#pragma unroll
    for (int c = 0; c < 4; ++c)
        wr[c] = (const float4*)(w + (size_t)(ob + c * 4 + og) * IN_DIM) + kq0;

    // ---- K loop: 4 t-steps of 64 k (16 g-lanes x float4), w dbl-buffered
    float4 wcur[4], wnxt[4];
#pragma unroll
    for (int c = 0; c < 4; ++c) wcur[c] = wr[c][g];

#pragma unroll
    for (int t = 0; t < 4; ++t) {
        if (t < 3) {
#pragma unroll
            for (int c = 0; c < 4; ++c) wnxt[c] = wr[c][(t + 1) * 16 + g];
        }
        const int kq = kq0 + t * 16 + g;
#pragma unroll
        for (int j = 0; j < 8; ++j) {
            const float4 xv = xs[j * 256 + kq];
#pragma unroll
            for (int c = 0; c < 4; ++c) {
                const float s0 = wcur[c].x + xv.x;
                const float s1 = wcur[c].y + xv.y;
                const float s2 = wcur[c].z + xv.z;
                const float s3 = wcur[c].w + xv.w;
                const float m = fmaxf(fmaxf(s0, s1), s2);   // v_max3
                acc[c][j] = fmaxf(fmaxf(m, s3), acc[c][j]); // v_max3
            }
        }
#pragma unroll
        for (int c = 0; c < 4; ++c) wcur[c] = wnxt[c];
    }

    // ---- reduce across the 16 k-phases (lane bits 0..3) ----
#pragma unroll
    for (int c = 0; c < 4; ++c)
#pragma unroll
        for (int j = 0; j < 8; ++j) {
            float v = acc[c][j];
            v = fmaxf(v, __shfl_xor(v, 1, 64));
            v = fmaxf(v, __shfl_xor(v, 2, 64));
            v = fmaxf(v, __shfl_xor(v, 4, 64));
            v = fmaxf(v, __shfl_xor(v, 8, 64));
            acc[c][j] = v;
        }

    // ---- cross-wave (k-quarter) reduce via LDS ----
    if (g == 0) {
#pragma unroll
        for (int c = 0; c < 4; ++c)
#pragma unroll
            for (int j = 0; j < 8; ++j)
                red[wid * 128 + og * 32 + c * 8 + j] = acc[c][j];
    }
    __syncthreads();

    if (tid < 128) {
        const int oo = tid & 15;     // 0..15 -> coalesced o
        const int j  = tid >> 4;     // 0..7
        const int cc = oo >> 2, og2 = oo & 3;
        const int base = og2 * 32 + cc * 8 + j;
        float v = fmaxf(fmaxf(red[base], red[128 + base]),
                        fmaxf(red[256 + base], red[384 + base]));
        out[(size_t)(n0 + j) * OUT_DIM + ob + oo] = v + bias[ob + oo];
    }
}

extern "C" void kernel_launch(void* const* d_in, const int* in_sizes, int n_in,
                              void* d_out, int out_size, void* d_ws, size_t ws_size,
                              hipStream_t stream) {
    const float* x    = (const float*)d_in[0];   // [128,1024]
    const float* w    = (const float*)d_in[1];   // [1024,1024]
    const float* bias = (const float*)d_in[2];   // [1024]
    float* out = (float*)d_out;                  // [128,1024]

    dim3 grid(1024);
    dim3 block(256);
    hipLaunchKernelGGL(tropical_linear_kernel, grid, block, 0, stream, x, w, bias, out);
}

// Round 6
// 68.603 us; speedup vs baseline: 1.0691x; 1.0097x over previous
//
#include <hip/hip_runtime.h>

#define N_ROWS 128
#define IN_DIM 1024
#define OUT_DIM 1024

// out[n,o] = max_k(w[o,k] + x[n,k]) + bias[o]   (tropical matmul)
//
// Pipe model per CU: VALU ~2.9 us, ds_read_b128 131k total -> ~2.6 us,
// w L2 traffic 64 MB -> ~1.9 us. R5 post-mortem fixes:
//  - __launch_bounds__(256,2): VGPR cap 256 (live set ~90) -> no spill, ever.
//  - G=8 k-phases, og=0..7: wave tile 8n x 32o, 4-way k-split across the
//    block's 4 waves -> 8 t-steps per wave (2x R5 amortization), butterfly
//    is 3 rounds not 4.
//  - #pragma unroll 1 on the t-loop so the compiler can't coalesce prefetch
//    stages and blow the live set; manual 2-deep w prefetch.
// Lane: g = lane&7 (k-phase), og = lane>>3 (o low 3 bits). Lane accumulates
// acc[c][j] for o = ob + c*8 + og (c=0..3), n = n0+j (j=0..7).
// Per t: 8 ds_read_b128 (128 B contiguous over g, 8-way og broadcast = free)
// + 4 coalesced w float4 loads (1 KB/instr over the wave) + 192 VALU.
// Grid: 16 bn x 32 bo = 512 blocks -> 2 blocks/CU, 8 waves/CU (2/SIMD).
// LDS: 32 KB x-tile + 4 KB reduce = 36 KB -> 72 KB/CU, fits.
// Epilogue: butterfly max over g (xor 1,2,4), g==0 writes red[], barrier,
// 256 threads do the 4-way k-quarter max + bias, coalesced store. Exact.

__global__ __launch_bounds__(256, 2)
void tropical_linear_kernel(const float* __restrict__ x,
                            const float* __restrict__ w,
                            const float* __restrict__ bias,
                            float* __restrict__ out) {
    __shared__ float4 xs[8 * 256];   // 32 KB: 8 n-rows x full K
    __shared__ float red[4 * 256];   // [wid][og][c][j] = 4 KB

    const int tid  = threadIdx.x;
    const int wid  = tid >> 6;       // wave 0..3 = k-quarter
    const int lane = tid & 63;
    const int g    = lane & 7;       // k phase 0..7
    const int og   = lane >> 3;      // o offset 0..7

    const int bn = blockIdx.x >> 5;  // 16 n-blocks
    const int bo = blockIdx.x & 31;  // 32 o-blocks
    const int n0 = bn * 8;
    const int ob = bo * 32;

    const float4* __restrict__ x4 = (const float4*)x;

    // ---- stage x tile: 2048 float4, 8 per thread, coalesced ----
#pragma unroll
    for (int i = 0; i < 8; ++i) {
        xs[tid + i * 256] = x4[(size_t)(n0 + i) * 256 + tid];
    }
    __syncthreads();

    float acc[4][8];
#pragma unroll
    for (int c = 0; c < 4; ++c)
#pragma unroll
        for (int j = 0; j < 8; ++j) acc[c][j] = -3.4e38f;

    const int kq0 = wid * 64;        // this wave's k-quarter (float4 units)
    const float4* __restrict__ wbase =
        (const float4*)(w + (size_t)(ob + og) * IN_DIM) + kq0 + g;

    // ---- K loop: 8 t-steps x 32 k, manual 2-deep w prefetch ----
    float4 wcur[4], wnxt[4];
#pragma unroll
    for (int c = 0; c < 4; ++c) wcur[c] = wbase[c * 8 * 256];

#pragma unroll 1
    for (int t = 0; t < 8; ++t) {
        if (t < 7) {
#pragma unroll
            for (int c = 0; c < 4; ++c) wnxt[c] = wbase[c * 8 * 256 + (t + 1) * 8];
        }
        const int kq = kq0 + t * 8 + g;
#pragma unroll
        for (int j = 0; j < 8; ++j) {
            const float4 xv = xs[j * 256 + kq];
#pragma unroll
            for (int c = 0; c < 4; ++c) {
                const float s0 = wcur[c].x + xv.x;
                const float s1 = wcur[c].y + xv.y;
                const float s2 = wcur[c].z + xv.z;
                const float s3 = wcur[c].w + xv.w;
                const float m = fmaxf(fmaxf(s0, s1), s2);   // v_max3
                acc[c][j] = fmaxf(fmaxf(m, s3), acc[c][j]); // v_max3
            }
        }
#pragma unroll
        for (int c = 0; c < 4; ++c) wcur[c] = wnxt[c];
    }

    // ---- reduce across the 8 k-phases (lane bits 0..2) ----
#pragma unroll
    for (int c = 0; c < 4; ++c)
#pragma unroll
        for (int j = 0; j < 8; ++j) {
            float v = acc[c][j];
            v = fmaxf(v, __shfl_xor(v, 1, 64));
            v = fmaxf(v, __shfl_xor(v, 2, 64));
            v = fmaxf(v, __shfl_xor(v, 4, 64));
            acc[c][j] = v;
        }

    // ---- cross-wave (k-quarter) reduce via LDS ----
    if (g == 0) {
#pragma unroll
        for (int c = 0; c < 4; ++c)
#pragma unroll
            for (int j = 0; j < 8; ++j)
                red[wid * 256 + og * 32 + c * 8 + j] = acc[c][j];
    }
    __syncthreads();

    {
        const int oo = tid & 31;     // 0..31 -> coalesced o within block
        const int j  = tid >> 5;     // 0..7
        const int cc = oo >> 3, og2 = oo & 7;
        const int base = og2 * 32 + cc * 8 + j;
        float v = fmaxf(fmaxf(red[base], red[256 + base]),
                        fmaxf(red[512 + base], red[768 + base]));
        out[(size_t)(n0 + j) * OUT_DIM + ob + oo] = v + bias[ob + oo];
    }
}

extern "C" void kernel_launch(void* const* d_in, const int* in_sizes, int n_in,
                              void* d_out, int out_size, void* d_ws, size_t ws_size,
                              hipStream_t stream) {
    const float* x    = (const float*)d_in[0];   // [128,1024]
    const float* w    = (const float*)d_in[1];   // [1024,1024]
    const float* bias = (const float*)d_in[2];   // [1024]
    float* out = (float*)d_out;                  // [128,1024]

    dim3 grid(512);
    dim3 block(256);
    hipLaunchKernelGGL(tropical_linear_kernel, grid, block, 0, stream, x, w, bias, out);
}

// Round 8
// 67.854 us; speedup vs baseline: 1.0809x; 1.0110x over previous
//
#include <hip/hip_runtime.h>

#define N_ROWS 128
#define IN_DIM 1024
#define OUT_DIM 1024

// out[n,o] = max_k(w[o,k] + x[n,k]) + bias[o]   (tropical matmul)
//
// R6 theory (unchanged; R7 was a compile fix — dpp_ctrl must be an
// immediate, now a template arg):
//  - k-phase reduce via explicit DPP (quad_perm xor1/xor2, row_half_mirror,
//    row_mirror): pure VALU, 0 LDS. (R5/R6 lesson: __shfl_xor =
//    ds_bpermute = LDS pipe; a 128-acc shfl butterfly costs ~5 us/CU.)
//  - No=4: each ds_read_b128 feeds 4 o-columns -> 131k ds_read total
//    -> ~2.6 us LDS pipe.
//  - 1024 blocks x 4 waves, __launch_bounds__(256,4) -> 16 waves/CU
//    (4/SIMD); w prefetched 2 t-steps ahead, ~110 VGPR (no spill).
// Layout: lane g=lane&15 (k-phase), og=lane>>4. Wave tile 8n x 16o
// (o = ob + c*4 + og, c=0..3), K split 4-way over waves (256 k each,
// 4 t-steps x 64 k). Per t: 8 ds_read_b128 (each feeds 4 o) + 4 coalesced
// w float4 loads + 192 VALU.
// Epilogue: 4 DPP max rounds over g; g==0 lanes -> LDS red (2 KB);
// cross-wave max + bias + coalesced store. All reductions exact.
// LDS 34 KB/block x 4 = 136 <= 160. Grid bn*64+bo: same-bo -> same XCD,
// 512 KB w band per XCD L2.

template <int CTRL>
__device__ __forceinline__ float dppmax(float v) {
    int vi = __builtin_bit_cast(int, v);
    int mi = __builtin_amdgcn_update_dpp(vi, vi, CTRL, 0xf, 0xf, false);
    return fmaxf(v, __builtin_bit_cast(float, mi));
}

__global__ __launch_bounds__(256, 4)
void tropical_linear_kernel(const float* __restrict__ x,
                            const float* __restrict__ w,
                            const float* __restrict__ bias,
                            float* __restrict__ out) {
    __shared__ float4 xs[8 * 256];    // 32 KB: 8 n-rows x full K
    __shared__ float red[4 * 16 * 8]; // [wid][oo][j] = 2 KB

    const int tid  = threadIdx.x;
    const int wid  = tid >> 6;       // wave 0..3 = k-quarter
    const int lane = tid & 63;
    const int g    = lane & 15;      // k phase 0..15
    const int og   = lane >> 4;      // o offset 0..3

    const int bn = blockIdx.x >> 6;  // 16 n-blocks
    const int bo = blockIdx.x & 63;  // 64 o-blocks (minor -> XCD locality)
    const int n0 = bn * 8;
    const int ob = bo * 16;

    const float4* __restrict__ x4 = (const float4*)x;

    // ---- stage x tile: 2048 float4, 8 per thread, coalesced ----
#pragma unroll
    for (int i = 0; i < 8; ++i) {
        xs[tid + i * 256] = x4[(size_t)(n0 + i) * 256 + tid];
    }
    __syncthreads();

    float acc[4][8];
#pragma unroll
    for (int c = 0; c < 4; ++c)
#pragma unroll
        for (int j = 0; j < 8; ++j) acc[c][j] = -3.4e38f;

    const int kq0 = wid * 64;        // this wave's k-quarter (float4 units)
    const float4* __restrict__ wr[4];
#pragma unroll
    for (int c = 0; c < 4; ++c)
        wr[c] = (const float4*)(w + (size_t)(ob + c * 4 + og) * IN_DIM) + kq0 + g;

    // ---- K loop: 4 t-steps x 64 k; w prefetched 2 t-steps ahead ----
    float4 wreg[4][4];               // [t][c], compiler-renamed
#pragma unroll
    for (int c = 0; c < 4; ++c) {
        wreg[0][c] = wr[c][0];
        wreg[1][c] = wr[c][16];
    }

#pragma unroll
    for (int t = 0; t < 4; ++t) {
        if (t + 2 < 4) {
#pragma unroll
            for (int c = 0; c < 4; ++c) wreg[t + 2][c] = wr[c][(t + 2) * 16];
        }
        const int kq = kq0 + t * 16 + g;
#pragma unroll
        for (int j = 0; j < 8; ++j) {
            const float4 xv = xs[j * 256 + kq];
#pragma unroll
            for (int c = 0; c < 4; ++c) {
                const float s0 = wreg[t][c].x + xv.x;
                const float s1 = wreg[t][c].y + xv.y;
                const float s2 = wreg[t][c].z + xv.z;
                const float s3 = wreg[t][c].w + xv.w;
                const float m = fmaxf(fmaxf(s0, s1), s2);   // v_max3
                acc[c][j] = fmaxf(fmaxf(m, s3), acc[c][j]); // v_max3
            }
        }
    }

    // ---- reduce across the 16 k-phases: DPP, pure VALU ----
    // quad_perm(1,0,3,2)=0xB1, quad_perm(2,3,0,1)=0x4E,
    // row_half_mirror=0x141, row_mirror=0x140 -> full row-of-16 reduce.
#pragma unroll
    for (int c = 0; c < 4; ++c)
#pragma unroll
        for (int j = 0; j < 8; ++j) {
            float v = acc[c][j];
            v = dppmax<0xB1>(v);
            v = dppmax<0x4E>(v);
            v = dppmax<0x141>(v);
            v = dppmax<0x140>(v);
            acc[c][j] = v;
        }

    // ---- cross-wave (k-quarter) reduce via LDS ----
    if (g == 0) {
#pragma unroll
        for (int c = 0; c < 4; ++c) {
            const int oo = c * 4 + og;
            // pack j in float4 pairs -> 2x ds_write_b128 per c
            *(float4*)&red[wid * 128 + oo * 8 + 0] =
                make_float4(acc[c][0], acc[c][1], acc[c][2], acc[c][3]);
            *(float4*)&red[wid * 128 + oo * 8 + 4] =
                make_float4(acc[c][4], acc[c][5], acc[c][6], acc[c][7]);
        }
    }
    __syncthreads();

    if (tid < 128) {
        const int oo = tid & 15;     // coalesced o
        const int j  = tid >> 4;     // 0..7
        const int base = oo * 8 + j;
        float v = fmaxf(fmaxf(red[base], red[128 + base]),
                        fmaxf(red[256 + base], red[384 + base]));
        out[(size_t)(n0 + j) * OUT_DIM + ob + oo] = v + bias[ob + oo];
    }
}

extern "C" void kernel_launch(void* const* d_in, const int* in_sizes, int n_in,
                              void* d_out, int out_size, void* d_ws, size_t ws_size,
                              hipStream_t stream) {
    const float* x    = (const float*)d_in[0];   // [128,1024]
    const float* w    = (const float*)d_in[1];   // [1024,1024]
    const float* bias = (const float*)d_in[2];   // [1024]
    float* out = (float*)d_out;                  // [128,1024]

    dim3 grid(1024);
    dim3 block(256);
    hipLaunchKernelGGL(tropical_linear_kernel, grid, block, 0, stream, x, w, bias, out);
}